// Round 1
// baseline (1110.145 us; speedup 1.0000x reference)
//
#include <hip/hip_runtime.h>
#include <cstddef>
#include <cstdint>

#define N_USERS 100000
#define N_ITEMS 50000
#define N_NODES 150000
#define N_EDGES 3000000
// EMBED_DIM = 64 == wavefront size: lane d owns dim d of a row.

// ---------------- init: cur = concat(user,item); out = 0.25*cur ----------------
__global__ __launch_bounds__(256) void k_init(const float* __restrict__ user,
                                              const float* __restrict__ item,
                                              float* __restrict__ cur,
                                              float* __restrict__ out) {
    int i = blockIdx.x * blockDim.x + threadIdx.x;          // float4 index
    const int total4 = N_NODES * 16;                        // 2,400,000
    if (i >= total4) return;
    const int user4 = N_USERS * 16;                         // 1,600,000
    float4 v = (i < user4) ? ((const float4*)user)[i]
                           : ((const float4*)item)[i - user4];
    ((float4*)cur)[i] = v;
    ((float4*)out)[i] = make_float4(0.25f * v.x, 0.25f * v.y,
                                    0.25f * v.z, 0.25f * v.w);
}

// ---------------- CSR build ----------------
__global__ __launch_bounds__(256) void k_hist(const int* __restrict__ rows,
                                              int* __restrict__ cnt) {
    int i = blockIdx.x * blockDim.x + threadIdx.x;
    if (i < N_EDGES) atomicAdd(&cnt[rows[i]], 1);
}

// single-block exclusive scan of cnt[0..N_NODES) -> row_start, cursor
__global__ __launch_bounds__(1024) void k_scan(const int* __restrict__ cnt,
                                               int* __restrict__ row_start,
                                               int* __restrict__ cursor) {
    const int T = 1024;
    const int CHUNK = (N_NODES + T - 1) / T;                // 147
    __shared__ int ssum[T];
    int t = threadIdx.x;
    int base = t * CHUNK;
    int local = 0;
    for (int j = 0; j < CHUNK; ++j) {
        int idx = base + j;
        if (idx < N_NODES) local += cnt[idx];
    }
    ssum[t] = local;
    __syncthreads();
    // Hillis-Steele inclusive scan over the 1024 per-thread sums
    for (int off = 1; off < T; off <<= 1) {
        int add = (t >= off) ? ssum[t - off] : 0;
        __syncthreads();
        if (t >= off) ssum[t] += add;
        __syncthreads();
    }
    int run = (t == 0) ? 0 : ssum[t - 1];                   // exclusive block offset
    for (int j = 0; j < CHUNK; ++j) {
        int idx = base + j;
        if (idx < N_NODES) {
            int c = cnt[idx];
            row_start[idx] = run;
            cursor[idx]    = run;
            run += c;
        }
    }
    if (t == T - 1) row_start[N_NODES] = ssum[T - 1];       // total = N_EDGES
}

__global__ __launch_bounds__(256) void k_scatter(const int* __restrict__ rows,
                                                 const int* __restrict__ cols,
                                                 const float* __restrict__ vals,
                                                 int* __restrict__ cursor,
                                                 int* __restrict__ cols_s,
                                                 float* __restrict__ vals_s) {
    int i = blockIdx.x * blockDim.x + threadIdx.x;
    if (i >= N_EDGES) return;
    int r = rows[i];
    int p = atomicAdd(&cursor[r], 1);
    cols_s[p] = cols[i];
    vals_s[p] = vals[i];
}

// ---------------- gather SpMM: one wave per row, lane = dim ----------------
// y[r] = sum vals*x[col];  out[r] += 0.25*y[r]  (scale folded, no extra pass)
__global__ __launch_bounds__(256) void k_spmm(const int* __restrict__ row_start,
                                              const int* __restrict__ cols_s,
                                              const float* __restrict__ vals_s,
                                              const float* __restrict__ x,
                                              float* __restrict__ y,
                                              float* __restrict__ out) {
    int gid = blockIdx.x * blockDim.x + threadIdx.x;
    int r = gid >> 6;
    int lane = threadIdx.x & 63;
    if (r >= N_NODES) return;
    int s = __builtin_amdgcn_readfirstlane(row_start[r]);
    int e = __builtin_amdgcn_readfirstlane(row_start[r + 1]);
    float acc = 0.f;
    int i = s;
    // 4-way unroll: 4 independent col/val loads then 4 independent 256B gathers
    for (; i + 4 <= e; i += 4) {
        int   c0 = cols_s[i],   c1 = cols_s[i+1], c2 = cols_s[i+2], c3 = cols_s[i+3];
        float v0 = vals_s[i],   v1 = vals_s[i+1], v2 = vals_s[i+2], v3 = vals_s[i+3];
        float x0 = x[c0 * 64 + lane];
        float x1 = x[c1 * 64 + lane];
        float x2 = x[c2 * 64 + lane];
        float x3 = x[c3 * 64 + lane];
        acc += v0 * x0; acc += v1 * x1; acc += v2 * x2; acc += v3 * x3;
    }
    for (; i < e; ++i) acc += vals_s[i] * x[cols_s[i] * 64 + lane];
    int o = r * 64 + lane;
    y[o] = acc;
    out[o] += 0.25f * acc;
}

// ---------------- fallback path (ws too small): atomic scatter SpMM ----------------
__global__ __launch_bounds__(256) void k_edge_atomic(const int* __restrict__ rows,
                                                     const int* __restrict__ cols,
                                                     const float* __restrict__ vals,
                                                     const float* __restrict__ x,
                                                     float* __restrict__ y) {
    long long gid = (long long)blockIdx.x * blockDim.x + threadIdx.x;
    int e = (int)(gid >> 6);
    int lane = threadIdx.x & 63;
    if (e >= N_EDGES) return;
    int r = rows[e], c = cols[e];
    float v = vals[e];
    atomicAdd(&y[r * 64 + lane], v * x[c * 64 + lane]);
}

__global__ __launch_bounds__(256) void k_accum(const float* __restrict__ y,
                                               float* __restrict__ out) {
    int i = blockIdx.x * blockDim.x + threadIdx.x;
    const int total4 = N_NODES * 16;
    if (i >= total4) return;
    float4 a = ((const float4*)y)[i];
    float4 o = ((float4*)out)[i];
    o.x += 0.25f * a.x; o.y += 0.25f * a.y;
    o.z += 0.25f * a.z; o.w += 0.25f * a.w;
    ((float4*)out)[i] = o;
}

extern "C" void kernel_launch(void* const* d_in, const int* in_sizes, int n_in,
                              void* d_out, int out_size, void* d_ws, size_t ws_size,
                              hipStream_t stream) {
    const float* user = (const float*)d_in[0];
    const float* item = (const float*)d_in[1];
    const int*   rows = (const int*)d_in[2];
    const int*   cols = (const int*)d_in[3];
    const float* vals = (const float*)d_in[4];
    float* out = (float*)d_out;

    const int INIT_BLOCKS  = (N_NODES * 16 + 255) / 256;       // 9375
    const int EDGE_BLOCKS  = (N_EDGES + 255) / 256;            // 11719
    const int SPMM_BLOCKS  = (N_NODES * 64 + 255) / 256;       // 37500

    auto align256 = [](size_t x) { return (x + 255) & ~(size_t)255; };
    const size_t sz_emb  = align256((size_t)N_NODES * 64 * sizeof(float)); // 38.4 MB
    const size_t sz_edge = align256((size_t)N_EDGES * sizeof(int));        // 12 MB
    const size_t sz_rs   = align256((size_t)(N_NODES + 1) * sizeof(int));
    const size_t need_csr = 2 * sz_emb + 2 * sz_edge + 3 * sz_rs;          // ~103 MB

    char* p = (char*)d_ws;
    if (ws_size >= need_csr) {
        float* cur       = (float*)p; p += sz_emb;
        float* nxt       = (float*)p; p += sz_emb;
        int*   cols_s    = (int*)p;   p += sz_edge;
        float* vals_s    = (float*)p; p += sz_edge;
        int*   row_start = (int*)p;   p += sz_rs;
        int*   cursor    = (int*)p;   p += sz_rs;
        int*   cnt       = (int*)p;   p += sz_rs;

        hipMemsetAsync(cnt, 0, (size_t)N_NODES * sizeof(int), stream);
        k_init<<<INIT_BLOCKS, 256, 0, stream>>>(user, item, cur, out);
        k_hist<<<EDGE_BLOCKS, 256, 0, stream>>>(rows, cnt);
        k_scan<<<1, 1024, 0, stream>>>(cnt, row_start, cursor);
        k_scatter<<<EDGE_BLOCKS, 256, 0, stream>>>(rows, cols, vals, cursor, cols_s, vals_s);

        // layer 1: cur -> nxt ; layer 2: nxt -> cur ; layer 3: cur -> nxt
        k_spmm<<<SPMM_BLOCKS, 256, 0, stream>>>(row_start, cols_s, vals_s, cur, nxt, out);
        k_spmm<<<SPMM_BLOCKS, 256, 0, stream>>>(row_start, cols_s, vals_s, nxt, cur, out);
        k_spmm<<<SPMM_BLOCKS, 256, 0, stream>>>(row_start, cols_s, vals_s, cur, nxt, out);
    } else {
        // fallback: atomic scatter SpMM, needs only 2 embedding buffers (~77 MB)
        float* bufA = (float*)p; p += sz_emb;
        float* bufB = (float*)p; p += sz_emb;
        float* in   = bufA;
        float* y    = bufB;
        const long long EA_THREADS = (long long)N_EDGES * 64;
        const int EA_BLOCKS = (int)((EA_THREADS + 255) / 256);  // 750000

        k_init<<<INIT_BLOCKS, 256, 0, stream>>>(user, item, in, out);
        for (int l = 0; l < 3; ++l) {
            hipMemsetAsync(y, 0, (size_t)N_NODES * 64 * sizeof(float), stream);
            k_edge_atomic<<<EA_BLOCKS, 256, 0, stream>>>(rows, cols, vals, in, y);
            k_accum<<<INIT_BLOCKS, 256, 0, stream>>>(y, out);
            float* t = in; in = y; y = t;
        }
    }
}

// Round 2
// 738.769 us; speedup vs baseline: 1.5027x; 1.5027x over previous
//
#include <hip/hip_runtime.h>
#include <cstddef>
#include <cstdint>

#define N_USERS 100000
#define N_ITEMS 50000
#define N_NODES 150000
#define N_EDGES 3000000
// EMBED_DIM = 64 == wavefront size: lane d owns dim d of a row.

// ---------------- init: cur = concat(user,item); out = 0.25*cur ----------------
__global__ __launch_bounds__(256) void k_init(const float* __restrict__ user,
                                              const float* __restrict__ item,
                                              float* __restrict__ cur,
                                              float* __restrict__ out) {
    int i = blockIdx.x * blockDim.x + threadIdx.x;          // float4 index
    const int total4 = N_NODES * 16;                        // 2,400,000
    if (i >= total4) return;
    const int user4 = N_USERS * 16;                         // 1,600,000
    float4 v = (i < user4) ? ((const float4*)user)[i]
                           : ((const float4*)item)[i - user4];
    ((float4*)cur)[i] = v;
    ((float4*)out)[i] = make_float4(0.25f * v.x, 0.25f * v.y,
                                    0.25f * v.z, 0.25f * v.w);
}

// ---------------- CSR build ----------------
__global__ __launch_bounds__(256) void k_hist(const int* __restrict__ rows,
                                              int* __restrict__ cnt) {
    int i = blockIdx.x * blockDim.x + threadIdx.x;
    if (i < N_EDGES) atomicAdd(&cnt[rows[i]], 1);
}

// ---- 3-phase multi-block exclusive scan of cnt[0..N_NODES) ----
// Each block covers 1024 elements (256 threads x 4).  NB = ceil(N/1024) = 147.

__global__ __launch_bounds__(256) void k_reduce(const int* __restrict__ cnt,
                                                int* __restrict__ blockSums) {
    int b = blockIdx.x, t = threadIdx.x;
    int base = b * 1024 + t * 4;
    int s = 0;
    if (base + 4 <= N_NODES) {
        int4 v = *(const int4*)(cnt + base);
        s = v.x + v.y + v.z + v.w;
    } else {
        for (int j = 0; j < 4; ++j) { int idx = base + j; if (idx < N_NODES) s += cnt[idx]; }
    }
    for (int off = 32; off; off >>= 1) s += __shfl_down(s, off, 64);
    __shared__ int wsum[4];
    if ((t & 63) == 0) wsum[t >> 6] = s;
    __syncthreads();
    if (t == 0) blockSums[b] = wsum[0] + wsum[1] + wsum[2] + wsum[3];
}

__global__ __launch_bounds__(256) void k_scan_block(const int* __restrict__ blockSums,
                                                    int* __restrict__ blockOffs, int nb) {
    __shared__ int sh[256];
    int t = threadIdx.x;
    sh[t] = (t < nb) ? blockSums[t] : 0;
    __syncthreads();
    for (int off = 1; off < 256; off <<= 1) {
        int add = (t >= off) ? sh[t - off] : 0;
        __syncthreads();
        sh[t] += add;
        __syncthreads();
    }
    if (t < nb) blockOffs[t] = (t == 0) ? 0 : sh[t - 1];
}

__global__ __launch_bounds__(256) void k_scan_apply(const int* __restrict__ cnt,
                                                    const int* __restrict__ blockOffs,
                                                    int* __restrict__ row_start,
                                                    int* __restrict__ cursor) {
    int b = blockIdx.x, t = threadIdx.x;
    int base = b * 1024 + t * 4;
    int c[4]; int s = 0;
    for (int j = 0; j < 4; ++j) {
        int idx = base + j;
        c[j] = (idx < N_NODES) ? cnt[idx] : 0;
        s += c[j];
    }
    __shared__ int sh[256];
    sh[t] = s;
    __syncthreads();
    for (int off = 1; off < 256; off <<= 1) {
        int add = (t >= off) ? sh[t - off] : 0;
        __syncthreads();
        sh[t] += add;
        __syncthreads();
    }
    int run = blockOffs[b] + ((t == 0) ? 0 : sh[t - 1]);
    for (int j = 0; j < 4; ++j) {
        int idx = base + j;
        if (idx < N_NODES) { row_start[idx] = run; cursor[idx] = run; run += c[j]; }
    }
    if (b == 0 && t == 0) row_start[N_NODES] = N_EDGES;
}

__global__ __launch_bounds__(256) void k_scatter(const int* __restrict__ rows,
                                                 const int* __restrict__ cols,
                                                 const float* __restrict__ vals,
                                                 int* __restrict__ cursor,
                                                 int* __restrict__ cols_s,
                                                 float* __restrict__ vals_s) {
    int i = blockIdx.x * blockDim.x + threadIdx.x;
    if (i >= N_EDGES) return;
    int r = rows[i];
    int p = atomicAdd(&cursor[r], 1);
    cols_s[p] = cols[i];
    vals_s[p] = vals[i];
}

// ---------------- gather SpMM: one wave per row, lane = dim ----------------
// y[r] = sum vals*x[col];  out[r] += 0.25*y[r]  (scale folded, no extra pass)
__global__ __launch_bounds__(256) void k_spmm(const int* __restrict__ row_start,
                                              const int* __restrict__ cols_s,
                                              const float* __restrict__ vals_s,
                                              const float* __restrict__ x,
                                              float* __restrict__ y,
                                              float* __restrict__ out) {
    int gid = blockIdx.x * blockDim.x + threadIdx.x;
    int r = gid >> 6;
    int lane = threadIdx.x & 63;
    if (r >= N_NODES) return;
    int s = __builtin_amdgcn_readfirstlane(row_start[r]);
    int e = __builtin_amdgcn_readfirstlane(row_start[r + 1]);
    float acc = 0.f;
    int i = s;
    // 4-way unroll: 4 independent col/val loads then 4 independent 256B gathers
    for (; i + 4 <= e; i += 4) {
        int   c0 = cols_s[i],   c1 = cols_s[i+1], c2 = cols_s[i+2], c3 = cols_s[i+3];
        float v0 = vals_s[i],   v1 = vals_s[i+1], v2 = vals_s[i+2], v3 = vals_s[i+3];
        float x0 = x[c0 * 64 + lane];
        float x1 = x[c1 * 64 + lane];
        float x2 = x[c2 * 64 + lane];
        float x3 = x[c3 * 64 + lane];
        acc += v0 * x0; acc += v1 * x1; acc += v2 * x2; acc += v3 * x3;
    }
    for (; i < e; ++i) acc += vals_s[i] * x[cols_s[i] * 64 + lane];
    int o = r * 64 + lane;
    y[o] = acc;
    out[o] += 0.25f * acc;
}

// ---------------- fallback path (ws too small): atomic scatter SpMM ----------------
__global__ __launch_bounds__(256) void k_edge_atomic(const int* __restrict__ rows,
                                                     const int* __restrict__ cols,
                                                     const float* __restrict__ vals,
                                                     const float* __restrict__ x,
                                                     float* __restrict__ y) {
    long long gid = (long long)blockIdx.x * blockDim.x + threadIdx.x;
    int e = (int)(gid >> 6);
    int lane = threadIdx.x & 63;
    if (e >= N_EDGES) return;
    int r = rows[e], c = cols[e];
    float v = vals[e];
    atomicAdd(&y[r * 64 + lane], v * x[c * 64 + lane]);
}

__global__ __launch_bounds__(256) void k_accum(const float* __restrict__ y,
                                               float* __restrict__ out) {
    int i = blockIdx.x * blockDim.x + threadIdx.x;
    const int total4 = N_NODES * 16;
    if (i >= total4) return;
    float4 a = ((const float4*)y)[i];
    float4 o = ((float4*)out)[i];
    o.x += 0.25f * a.x; o.y += 0.25f * a.y;
    o.z += 0.25f * a.z; o.w += 0.25f * a.w;
    ((float4*)out)[i] = o;
}

extern "C" void kernel_launch(void* const* d_in, const int* in_sizes, int n_in,
                              void* d_out, int out_size, void* d_ws, size_t ws_size,
                              hipStream_t stream) {
    const float* user = (const float*)d_in[0];
    const float* item = (const float*)d_in[1];
    const int*   rows = (const int*)d_in[2];
    const int*   cols = (const int*)d_in[3];
    const float* vals = (const float*)d_in[4];
    float* out = (float*)d_out;

    const int INIT_BLOCKS  = (N_NODES * 16 + 255) / 256;       // 9375
    const int EDGE_BLOCKS  = (N_EDGES + 255) / 256;            // 11719
    const int SPMM_BLOCKS  = (N_NODES * 64 + 255) / 256;       // 37500
    const int SCAN_BLOCKS  = (N_NODES + 1023) / 1024;          // 147

    auto align256 = [](size_t x) { return (x + 255) & ~(size_t)255; };
    const size_t sz_emb  = align256((size_t)N_NODES * 64 * sizeof(float)); // 38.4 MB
    const size_t sz_edge = align256((size_t)N_EDGES * sizeof(int));        // 12 MB
    const size_t sz_rs   = align256((size_t)(N_NODES + 1) * sizeof(int));
    const size_t sz_bs   = align256((size_t)SCAN_BLOCKS * sizeof(int));
    const size_t need_csr = 2 * sz_emb + 2 * sz_edge + 3 * sz_rs + 2 * sz_bs; // ~103 MB

    char* p = (char*)d_ws;
    if (ws_size >= need_csr) {
        float* cur       = (float*)p; p += sz_emb;
        float* nxt       = (float*)p; p += sz_emb;
        int*   cols_s    = (int*)p;   p += sz_edge;
        float* vals_s    = (float*)p; p += sz_edge;
        int*   row_start = (int*)p;   p += sz_rs;
        int*   cursor    = (int*)p;   p += sz_rs;
        int*   cnt       = (int*)p;   p += sz_rs;
        int*   blockSums = (int*)p;   p += sz_bs;
        int*   blockOffs = (int*)p;   p += sz_bs;

        hipMemsetAsync(cnt, 0, (size_t)N_NODES * sizeof(int), stream);
        k_init<<<INIT_BLOCKS, 256, 0, stream>>>(user, item, cur, out);
        k_hist<<<EDGE_BLOCKS, 256, 0, stream>>>(rows, cnt);
        k_reduce<<<SCAN_BLOCKS, 256, 0, stream>>>(cnt, blockSums);
        k_scan_block<<<1, 256, 0, stream>>>(blockSums, blockOffs, SCAN_BLOCKS);
        k_scan_apply<<<SCAN_BLOCKS, 256, 0, stream>>>(cnt, blockOffs, row_start, cursor);
        k_scatter<<<EDGE_BLOCKS, 256, 0, stream>>>(rows, cols, vals, cursor, cols_s, vals_s);

        // layer 1: cur -> nxt ; layer 2: nxt -> cur ; layer 3: cur -> nxt
        k_spmm<<<SPMM_BLOCKS, 256, 0, stream>>>(row_start, cols_s, vals_s, cur, nxt, out);
        k_spmm<<<SPMM_BLOCKS, 256, 0, stream>>>(row_start, cols_s, vals_s, nxt, cur, out);
        k_spmm<<<SPMM_BLOCKS, 256, 0, stream>>>(row_start, cols_s, vals_s, cur, nxt, out);
    } else {
        // fallback: atomic scatter SpMM, needs only 2 embedding buffers (~77 MB)
        float* bufA = (float*)p; p += sz_emb;
        float* bufB = (float*)p; p += sz_emb;
        float* in   = bufA;
        float* y    = bufB;
        const long long EA_THREADS = (long long)N_EDGES * 64;
        const int EA_BLOCKS = (int)((EA_THREADS + 255) / 256);  // 750000

        k_init<<<INIT_BLOCKS, 256, 0, stream>>>(user, item, in, out);
        for (int l = 0; l < 3; ++l) {
            hipMemsetAsync(y, 0, (size_t)N_NODES * 64 * sizeof(float), stream);
            k_edge_atomic<<<EA_BLOCKS, 256, 0, stream>>>(rows, cols, vals, in, y);
            k_accum<<<INIT_BLOCKS, 256, 0, stream>>>(y, out);
            float* t = in; in = y; y = t;
        }
    }
}

// Round 3
// 477.189 us; speedup vs baseline: 2.3264x; 1.5482x over previous
//
#include <hip/hip_runtime.h>
#include <cstddef>
#include <cstdint>

#define N_USERS 100000
#define N_ITEMS 50000
#define N_NODES 150000
#define N_EDGES 3000000
// EMBED_DIM = 64 == wavefront size: lane d owns dim d of a row.

#define NBKT 293          // ceil(150000 / 512) buckets of 512 rows
#define BCHUNK 8192       // edges per multisplit block
#define ABLK ((N_EDGES + BCHUNK - 1) / BCHUNK)   // 367

// ---------------- phase A: bucket counts (LDS hist -> 293 global adds/block) ----
__global__ __launch_bounds__(256) void k_bucket_count(const int* __restrict__ rows,
                                                      int* __restrict__ bucket_cnt) {
    __shared__ int hist[NBKT];
    int t = threadIdx.x;
    for (int j = t; j < NBKT; j += 256) hist[j] = 0;
    __syncthreads();
    int s0 = blockIdx.x * BCHUNK;
    int e0 = min(s0 + BCHUNK, N_EDGES);
    for (int i = s0 + t; i < e0; i += 256)
        atomicAdd(&hist[rows[i] >> 9], 1);
    __syncthreads();
    for (int j = t; j < NBKT; j += 256)
        if (hist[j]) atomicAdd(&bucket_cnt[j], hist[j]);
}

// ---------------- tiny scan of 293 bucket counts ----------------
__global__ __launch_bounds__(512) void k_bucket_scan(const int* __restrict__ bucket_cnt,
                                                     int* __restrict__ bucket_start,
                                                     int* __restrict__ bucket_cursor,
                                                     int* __restrict__ row_start) {
    __shared__ int sh[512];
    int t = threadIdx.x;
    sh[t] = (t < NBKT) ? bucket_cnt[t] : 0;
    __syncthreads();
    for (int off = 1; off < 512; off <<= 1) {
        int add = (t >= off) ? sh[t - off] : 0;
        __syncthreads();
        sh[t] += add;
        __syncthreads();
    }
    if (t < NBKT) {
        int st = (t == 0) ? 0 : sh[t - 1];
        bucket_start[t] = st;
        bucket_cursor[t] = st;
    }
    if (t == 0) { bucket_start[NBKT] = N_EDGES; row_start[N_NODES] = N_EDGES; }
}

// ---------------- phase B: bucket scatter (block-local runs -> full lines) ------
// packs (col 18b | row_lo 9b << 18, val) into int2
__global__ __launch_bounds__(256) void k_bucket_scatter(const int* __restrict__ rows,
                                                        const int* __restrict__ cols,
                                                        const float* __restrict__ vals,
                                                        int* __restrict__ bucket_cursor,
                                                        int2* __restrict__ ebuf) {
    __shared__ int hist[NBKT];
    __shared__ int base[NBKT];
    int t = threadIdx.x;
    for (int j = t; j < NBKT; j += 256) hist[j] = 0;
    __syncthreads();
    int s0 = blockIdx.x * BCHUNK;
    int e0 = min(s0 + BCHUNK, N_EDGES);
    for (int i = s0 + t; i < e0; i += 256)
        atomicAdd(&hist[rows[i] >> 9], 1);
    __syncthreads();
    for (int j = t; j < NBKT; j += 256) {
        int c = hist[j];
        base[j] = c ? atomicAdd(&bucket_cursor[j], c) : 0;
    }
    for (int j = t; j < NBKT; j += 256) hist[j] = 0;
    __syncthreads();
    for (int i = s0 + t; i < e0; i += 256) {
        int r = rows[i];
        int b = r >> 9;
        int off = atomicAdd(&hist[b], 1);
        ebuf[base[b] + off] = make_int2(cols[i] | ((r & 511) << 18),
                                        __float_as_int(vals[i]));
    }
}

// ---------------- phase C: per-bucket sort to CSR + row_start emission ----------
__global__ __launch_bounds__(256) void k_sort_bucket(const int2* __restrict__ ebuf,
                                                     const int* __restrict__ bucket_start,
                                                     int* __restrict__ row_start,
                                                     int* __restrict__ cols_s,
                                                     float* __restrict__ vals_s) {
    __shared__ int rcnt[512];
    __shared__ int psum[256];
    __shared__ int curs[512];
    int b = blockIdx.x, t = threadIdx.x;
    int rbase = b << 9;
    rcnt[2 * t] = 0; rcnt[2 * t + 1] = 0;
    __syncthreads();
    int s = bucket_start[b], e = bucket_start[b + 1];
    for (int i = s + t; i < e; i += 256)
        atomicAdd(&rcnt[(ebuf[i].x >> 18) & 511], 1);
    __syncthreads();
    int a0 = rcnt[2 * t], a1 = rcnt[2 * t + 1];
    psum[t] = a0 + a1;
    __syncthreads();
    for (int off = 1; off < 256; off <<= 1) {
        int add = (t >= off) ? psum[t - off] : 0;
        __syncthreads();
        psum[t] += add;
        __syncthreads();
    }
    int ex = (t == 0) ? 0 : psum[t - 1];
    int r0 = s + ex;            // absolute CSR start of row rbase+2t
    int r1 = r0 + a0;
    curs[2 * t] = r0; curs[2 * t + 1] = r1;
    int rr = rbase + 2 * t;
    if (rr < N_NODES)     row_start[rr] = r0;
    if (rr + 1 < N_NODES) row_start[rr + 1] = r1;
    __syncthreads();
    for (int i = s + t; i < e; i += 256) {
        int2 ed = ebuf[i];
        int pos = atomicAdd(&curs[(ed.x >> 18) & 511], 1);
        cols_s[pos] = ed.x & 0x3FFFF;
        vals_s[pos] = __int_as_float(ed.y);
    }
}

// ---------------- gather SpMM: one wave per row, lane = dim ----------------
// LAYER 1: gather from user/item split, out = 0.25*(e0 + acc) pure store, y=acc
// LAYER 2: gather from x, y=acc, out += 0.25*acc
// LAYER 3: gather from x, no y write, out += 0.25*acc
template <int LAYER>
__global__ __launch_bounds__(256) void k_spmm(const int* __restrict__ row_start,
                                              const int* __restrict__ cols_s,
                                              const float* __restrict__ vals_s,
                                              const float* __restrict__ user,
                                              const float* __restrict__ item,
                                              const float* __restrict__ x,
                                              float* __restrict__ y,
                                              float* __restrict__ out) {
    int gid = blockIdx.x * blockDim.x + threadIdx.x;
    int r = gid >> 6;
    int lane = threadIdx.x & 63;
    if (r >= N_NODES) return;
    int s = __builtin_amdgcn_readfirstlane(row_start[r]);
    int e = __builtin_amdgcn_readfirstlane(row_start[r + 1]);
    float acc = 0.f;

    auto xload = [&](int c) -> float {
        if constexpr (LAYER == 1) {
            const float* xb = (c < N_USERS) ? (user + (size_t)c * 64)
                                            : (item + (size_t)(c - N_USERS) * 64);
            return xb[lane];
        } else {
            return x[(size_t)c * 64 + lane];
        }
    };

    int i = s;
    for (; i + 4 <= e; i += 4) {
        int   c0 = cols_s[i],   c1 = cols_s[i+1], c2 = cols_s[i+2], c3 = cols_s[i+3];
        float v0 = vals_s[i],   v1 = vals_s[i+1], v2 = vals_s[i+2], v3 = vals_s[i+3];
        float x0 = xload(c0), x1 = xload(c1), x2 = xload(c2), x3 = xload(c3);
        acc += v0 * x0; acc += v1 * x1; acc += v2 * x2; acc += v3 * x3;
    }
    for (; i < e; ++i) acc += vals_s[i] * xload(cols_s[i]);

    int o = r * 64 + lane;
    if constexpr (LAYER == 1) {
        float e0v = (r < N_USERS) ? user[(size_t)r * 64 + lane]
                                  : item[(size_t)(r - N_USERS) * 64 + lane];
        y[o] = acc;
        out[o] = 0.25f * (e0v + acc);
    } else if constexpr (LAYER == 2) {
        y[o] = acc;
        out[o] += 0.25f * acc;
    } else {
        out[o] += 0.25f * acc;
    }
}

// ---------------- fallback path (ws too small): atomic scatter SpMM ----------------
__global__ __launch_bounds__(256) void k_init(const float* __restrict__ user,
                                              const float* __restrict__ item,
                                              float* __restrict__ cur,
                                              float* __restrict__ out) {
    int i = blockIdx.x * blockDim.x + threadIdx.x;
    const int total4 = N_NODES * 16;
    if (i >= total4) return;
    const int user4 = N_USERS * 16;
    float4 v = (i < user4) ? ((const float4*)user)[i]
                           : ((const float4*)item)[i - user4];
    ((float4*)cur)[i] = v;
    ((float4*)out)[i] = make_float4(0.25f * v.x, 0.25f * v.y,
                                    0.25f * v.z, 0.25f * v.w);
}

__global__ __launch_bounds__(256) void k_edge_atomic(const int* __restrict__ rows,
                                                     const int* __restrict__ cols,
                                                     const float* __restrict__ vals,
                                                     const float* __restrict__ x,
                                                     float* __restrict__ y) {
    long long gid = (long long)blockIdx.x * blockDim.x + threadIdx.x;
    int e = (int)(gid >> 6);
    int lane = threadIdx.x & 63;
    if (e >= N_EDGES) return;
    int r = rows[e], c = cols[e];
    float v = vals[e];
    atomicAdd(&y[r * 64 + lane], v * x[c * 64 + lane]);
}

__global__ __launch_bounds__(256) void k_accum(const float* __restrict__ y,
                                               float* __restrict__ out) {
    int i = blockIdx.x * blockDim.x + threadIdx.x;
    const int total4 = N_NODES * 16;
    if (i >= total4) return;
    float4 a = ((const float4*)y)[i];
    float4 o = ((float4*)out)[i];
    o.x += 0.25f * a.x; o.y += 0.25f * a.y;
    o.z += 0.25f * a.z; o.w += 0.25f * a.w;
    ((float4*)out)[i] = o;
}

extern "C" void kernel_launch(void* const* d_in, const int* in_sizes, int n_in,
                              void* d_out, int out_size, void* d_ws, size_t ws_size,
                              hipStream_t stream) {
    const float* user = (const float*)d_in[0];
    const float* item = (const float*)d_in[1];
    const int*   rows = (const int*)d_in[2];
    const int*   cols = (const int*)d_in[3];
    const float* vals = (const float*)d_in[4];
    float* out = (float*)d_out;

    const int INIT_BLOCKS = (N_NODES * 16 + 255) / 256;        // 9375
    const int SPMM_BLOCKS = (N_NODES * 64 + 255) / 256;        // 37500

    auto align256 = [](size_t x) { return (x + 255) & ~(size_t)255; };
    const size_t sz_emb  = align256((size_t)N_NODES * 64 * sizeof(float)); // 38.4 MB
    const size_t sz_edge = align256((size_t)N_EDGES * sizeof(int));        // 12 MB
    const size_t sz_rs   = align256((size_t)(N_NODES + 1) * sizeof(int));
    const size_t sz_bk   = align256((size_t)(NBKT + 1) * sizeof(int));
    const size_t need_csr = 2 * sz_emb + 2 * sz_edge + sz_rs + 3 * sz_bk;  // ~101.5 MB

    char* p = (char*)d_ws;
    if (ws_size >= need_csr) {
        float* cur       = (float*)p; p += sz_emb;
        float* nxt       = (float*)p; p += sz_emb;   // ebuf (24 MB) aliases nxt (38.4 MB)
        int*   cols_s    = (int*)p;   p += sz_edge;
        float* vals_s    = (float*)p; p += sz_edge;
        int*   row_start = (int*)p;   p += sz_rs;
        int*   bucket_cnt    = (int*)p; p += sz_bk;
        int*   bucket_start  = (int*)p; p += sz_bk;
        int*   bucket_cursor = (int*)p; p += sz_bk;
        int2*  ebuf = (int2*)nxt;

        hipMemsetAsync(bucket_cnt, 0, (size_t)NBKT * sizeof(int), stream);
        k_bucket_count<<<ABLK, 256, 0, stream>>>(rows, bucket_cnt);
        k_bucket_scan<<<1, 512, 0, stream>>>(bucket_cnt, bucket_start, bucket_cursor, row_start);
        k_bucket_scatter<<<ABLK, 256, 0, stream>>>(rows, cols, vals, bucket_cursor, ebuf);
        k_sort_bucket<<<NBKT, 256, 0, stream>>>(ebuf, bucket_start, row_start, cols_s, vals_s);

        // layer 1: (user,item) -> nxt ; layer 2: nxt -> cur ; layer 3: cur -> (out only)
        k_spmm<1><<<SPMM_BLOCKS, 256, 0, stream>>>(row_start, cols_s, vals_s, user, item,
                                                   nullptr, nxt, out);
        k_spmm<2><<<SPMM_BLOCKS, 256, 0, stream>>>(row_start, cols_s, vals_s, user, item,
                                                   nxt, cur, out);
        k_spmm<3><<<SPMM_BLOCKS, 256, 0, stream>>>(row_start, cols_s, vals_s, user, item,
                                                   cur, nullptr, out);
    } else {
        // fallback: atomic scatter SpMM, needs only 2 embedding buffers (~77 MB)
        float* bufA = (float*)p; p += sz_emb;
        float* bufB = (float*)p; p += sz_emb;
        float* in   = bufA;
        float* y    = bufB;
        const long long EA_THREADS = (long long)N_EDGES * 64;
        const int EA_BLOCKS = (int)((EA_THREADS + 255) / 256);

        k_init<<<INIT_BLOCKS, 256, 0, stream>>>(user, item, in, out);
        for (int l = 0; l < 3; ++l) {
            hipMemsetAsync(y, 0, (size_t)N_NODES * 64 * sizeof(float), stream);
            k_edge_atomic<<<EA_BLOCKS, 256, 0, stream>>>(rows, cols, vals, in, y);
            k_accum<<<INIT_BLOCKS, 256, 0, stream>>>(y, out);
            float* t = in; in = y; y = t;
        }
    }
}